// Round 5
// baseline (94.606 us; speedup 1.0000x reference)
//
#include <hip/hip_runtime.h>
#include <math.h>

#define HH 76
#define WW 76
#define HW (HH*WW)          // 5776
#define AA 3
#define CC 80
#define TT 50
#define BS 8
#define NPB (AA*HW)         // cells per image: 17328
#define CHUNKS ((NPB + 255) / 256)   // 68
#define NBLK (CHUNKS*BS)             // 544 blocks

// ANCHORS / STRIDE(=8)
__constant__ float c_aw[9] = {17.75f, 24.0f, 57.375f, 4.5f, 9.5f, 9.0f, 1.5f, 2.375f, 5.0f};
__constant__ float c_ah[9] = {13.75f, 30.375f, 50.125f, 9.375f, 6.875f, 18.25f, 2.0f, 4.5f, 3.5f};

__device__ __forceinline__ float sigf(float x) { return 1.0f / (1.0f + expf(-x)); }

// One block = 256 consecutive cells of one image (blockIdx.y = b).
// R4->R5: hoist the 5 strided channel loads ABOVE target-prep/__syncthreads so
// their ~900-cycle HBM latency overlaps prep + barrier (only ~2 waves/SIMD are
// resident, so within-thread overlap is the only latency hiding available).
__global__ __launch_bounds__(256) void yolo_main(const float* __restrict__ in,
                                                 const float* __restrict__ tb,
                                                 const int* __restrict__ tc,
                                                 float* __restrict__ part)
{
    __shared__ float4 sA[TT];    // x1, y1, x2, y2 (gt corners)      [hot]
    __shared__ float2 sAL[TT];   // area_g, lin(bits)                [hot]
    __shared__ float4 sC[TT];    // gx, gy, gw, gh                   [rare]
    __shared__ float  sBls[TT];  // box loss scale                   [rare]
    __shared__ int    sCl[TT];   // class index                      [rare]
    __shared__ int4   q[256];    // matched-cell queue: n, b0, b1, b2
    __shared__ int    qcnt;
    __shared__ float  sCls;
    __shared__ float  sred[2][4];

    const int b = blockIdx.y;
    const int tid = threadIdx.x;

    if (tid == 0) { qcnt = 0; sCls = 0.0f; }

    // ---- issue the global channel loads FIRST (latency overlaps prep) ----
    const int n = blockIdx.x * 256 + tid;   // image-local cell index
    const bool live = (n < NPB);
    const int hw = n % HW;          // j*WW + i
    const int i  = n % WW;
    const int j  = (n / WW) % HH;
    const int a  = n / HW;
    const float* p = in + ((size_t)b*(AA*(5+CC)) + (size_t)a*(5+CC))*HW + hw;
    float tx = 0.f, ty = 0.f, tw = 0.f, th = 0.f, tcf = 0.f;
    if (live) {
        tx  = p[0];
        ty  = p[HW];
        tw  = p[2*HW];
        th  = p[3*HW];
        tcf = p[4*HW];
    }

    // ---- fused prep: 50 threads compute this image's targets ----
    if (tid < TT) {
        int t = b * TT + tid;
        float t0 = tb[t*4 + 0];
        float t1 = tb[t*4 + 1];
        float t2 = tb[t*4 + 2];
        float t3 = tb[t*4 + 3];
        float gx = t0 * (float)WW;
        float gy = t1 * (float)HH;
        float gw = t2 * (float)WW;
        float gh = t3 * (float)HH;

        int best = 0;
        float bestv = -1.0f;
        float ag = gw * gh;
        #pragma unroll
        for (int nn = 0; nn < 9; nn++) {
            float inter = fminf(gw, c_aw[nn]) * fminf(gh, c_ah[nn]);
            float uni   = ag + c_aw[nn]*c_ah[nn] - inter;
            float r = inter / uni;
            if (r > bestv) { bestv = r; best = nn; }
        }
        int gi = (int)floorf(gx);
        int gj = (int)floorf(gy);
        bool valid = (best >= 6) && (best < 9) && (gi < WW) && (gj < HH);
        int aa = best - 6; aa = aa < 0 ? 0 : (aa > 2 ? 2 : aa);
        int lin = valid ? ((aa*HH + gj)*WW + gi) : -1;   // image-local cell index

        sA[tid]   = make_float4(gx - 0.5f*gw, gy - 0.5f*gh, gx + 0.5f*gw, gy + 0.5f*gh);
        sAL[tid]  = make_float2(ag, __int_as_float(lin));
        sC[tid]   = make_float4(gx, gy, gw, gh);
        sBls[tid] = 2.0f - t2*t3;
        sCl[tid]  = tc[t];
    }
    __syncthreads();

    float accConf = 0.0f, accLoc = 0.0f;
    if (live) {
        float px = sigf(tx) + (float)i;
        float py = sigf(ty) + (float)j;
        float pw = expf(tw) * c_aw[6 + a];
        float ph = expf(th) * c_ah[6 + a];
        float conf = sigf(tcf);

        float p1x = px - 0.5f*pw, p2x = px + 0.5f*pw;
        float p1y = py - 0.5f*ph, p2y = py + 0.5f*ph;
        float areap = pw * ph;

        // ---- T=50 ignore loop: ds_read_b128 + ds_read_b64 per iter ----
        float ioumax = 0.0f;
        int match = -1;
        #pragma unroll 10
        for (int t = 0; t < TT; t++) {
            float4 A = sA[t];
            float2 L = sAL[t];
            float iw = fmaxf(fminf(A.z, p2x) - fmaxf(A.x, p1x), 0.0f);
            float ih = fmaxf(fminf(A.w, p2y) - fmaxf(A.y, p1y), 0.0f);
            float inter = iw * ih;
            float iou = inter * __builtin_amdgcn_rcpf(L.x + areap - inter);
            ioumax = fmaxf(ioumax, iou);
            if (__float_as_int(L.y) == n) match = t;   // last-write-wins
        }

        float pcl = fminf(fmaxf(conf, 1e-7f), 1.0f - 1e-7f);
        if (match >= 0) {
            accConf = -logf(pcl);
        } else if (ioumax <= 0.5f) {
            accConf = -logf(1.0f - pcl);
        }

        if (match >= 0) {
            // ---- CIoU loc loss (pure VALU, keep per-thread) ----
            float4 G = sC[match];
            float gx = G.x, gy = G.y, gw = G.z, gh = G.w;
            float bls = sBls[match];
            float g1x = gx - 0.5f*gw, g2x = gx + 0.5f*gw;
            float g1y = gy - 0.5f*gh, g2y = gy + 0.5f*gh;
            float iw = fmaxf(fminf(p2x, g2x) - fmaxf(p1x, g1x), 0.0f);
            float ih = fmaxf(fminf(p2y, g2y) - fmaxf(p1y, g1y), 0.0f);
            float inter = iw * ih;
            float uni = areap + gw*gh - inter;
            float iou = inter / fmaxf(uni, 1e-6f);
            float dx = px - gx, dy = py - gy;
            float cd = dx*dx + dy*dy;
            float ewx = fmaxf(fmaxf(p2x, g2x) - fminf(p1x, g1x), 0.0f);
            float ewy = fmaxf(fmaxf(p2y, g2y) - fminf(p1y, g1y), 0.0f);
            float ediag = ewx*ewx + ewy*ewy;
            float ciou = iou - cd / fmaxf(ediag, 1e-6f);
            float da = atanf(pw / fmaxf(ph, 1e-6f)) - atanf(gw / fmaxf(gh, 1e-6f));
            const float PI2INV4 = 4.0f / (float)(M_PI * M_PI);
            float v = PI2INV4 * da * da;
            float alpha = v / fmaxf(1.0f - iou + v, 1e-6f);
            ciou = ciou - alpha * v;
            accLoc = (1.0f - ciou) * bls;

            // class bit union over all matching targets (scatter-set semantics)
            unsigned b0 = 0, b1 = 0, b2 = 0;
            for (int t = 0; t < TT; t++) {
                if (__float_as_int(sAL[t].y) == n) {
                    int c = sCl[t];
                    if (c < 32) b0 |= 1u << c;
                    else if (c < 64) b1 |= 1u << (c - 32);
                    else b2 |= 1u << (c - 64);
                }
            }
            int slot = atomicAdd(&qcnt, 1);
            q[slot] = make_int4(n, (int)b0, (int)b1, (int)b2);
        }
    }
    __syncthreads();

    // ---- phase 2: cooperative class-BCE, one WAVE per queue entry ----
    const int wid = tid >> 6;
    const int lane = tid & 63;
    const int cnt = qcnt;
    for (int e = wid; e < cnt; e += 4) {
        int4 Q = q[e];
        int qn = Q.x;
        int qhw = qn % HW;
        int qa  = qn / HW;
        const float* pc = in + ((size_t)b*(AA*(5+CC)) + (size_t)qa*(5+CC) + 5)*HW + qhw;
        unsigned bits0 = (unsigned)Q.y, bits1 = (unsigned)Q.z, bits2 = (unsigned)Q.w;

        // lane handles class c = lane and c = lane + 64 (lanes 0..15)
        float lg0 = pc[(size_t)lane * HW];
        float lg1 = (lane < CC - 64) ? pc[(size_t)(lane + 64) * HW] : 0.0f;

        float s;
        {
            float pp = fminf(fmaxf(sigf(lg0), 1e-7f), 1.0f - 1e-7f);
            unsigned bit = (lane < 32 ? (bits0 >> lane) : (bits1 >> (lane - 32))) & 1u;
            s = -logf(bit ? pp : 1.0f - pp);
        }
        if (lane < CC - 64) {
            float pp = fminf(fmaxf(sigf(lg1), 1e-7f), 1.0f - 1e-7f);
            unsigned bit = (bits2 >> (lane + 64 - 64)) & 1u;
            s += -logf(bit ? pp : 1.0f - pp);
        }
        for (int off = 32; off > 0; off >>= 1) s += __shfl_down(s, off);
        if (lane == 0) atomicAdd(&sCls, s);
    }

    // ---- block reduction: conf + loc ----
    for (int off = 32; off > 0; off >>= 1) {
        accConf += __shfl_down(accConf, off);
        accLoc  += __shfl_down(accLoc,  off);
    }
    if (lane == 0) { sred[0][wid] = accConf; sred[1][wid] = accLoc; }
    __syncthreads();
    if (tid == 0) {
        float c0 = 0.f, c2 = 0.f;
        #pragma unroll
        for (int w = 0; w < 4; w++) { c0 += sred[0][w]; c2 += sred[1][w]; }
        const int bid = blockIdx.y * CHUNKS + blockIdx.x;
        part[0*NBLK + bid] = c0;    // conf
        part[1*NBLK + bid] = sCls;  // cls
        part[2*NBLK + bid] = c2;    // loc
    }
}

// ---- final reduce: 544 partials x 3 comps -> 4 outputs, one block ----
__global__ __launch_bounds__(256) void yolo_fin(const float* __restrict__ part,
                                                float* __restrict__ out)
{
    __shared__ float sred[3][4];
    float c0 = 0.f, c1 = 0.f, c2 = 0.f;
    for (int k = threadIdx.x; k < NBLK; k += 256) {
        c0 += part[0*NBLK + k];
        c1 += part[1*NBLK + k];
        c2 += part[2*NBLK + k];
    }
    for (int off = 32; off > 0; off >>= 1) {
        c0 += __shfl_down(c0, off);
        c1 += __shfl_down(c1, off);
        c2 += __shfl_down(c2, off);
    }
    int wid = threadIdx.x >> 6;
    int lane = threadIdx.x & 63;
    if (lane == 0) { sred[0][wid] = c0; sred[1][wid] = c1; sred[2][wid] = c2; }
    __syncthreads();
    if (threadIdx.x == 0) {
        float s0 = 0.f, s1 = 0.f, s2 = 0.f;
        #pragma unroll
        for (int w = 0; w < 4; w++) { s0 += sred[0][w]; s1 += sred[1][w]; s2 += sred[2][w]; }
        const float inv_bs = 1.0f / (float)BS;
        s0 *= inv_bs; s1 *= inv_bs; s2 *= inv_bs;
        out[0] = s0 + s1 + s2;
        out[1] = s0;
        out[2] = s1;
        out[3] = s2;
    }
}

extern "C" void kernel_launch(void* const* d_in, const int* in_sizes, int n_in,
                              void* d_out, int out_size, void* d_ws, size_t ws_size,
                              hipStream_t stream) {
    const float* inp = (const float*)d_in[0];          // (8, 255, 76, 76) fp32
    const float* tb  = (const float*)d_in[1];          // (8, 50, 4) fp32
    const int*   tc  = (const int*)d_in[2];            // (8, 50) int32
    float* out = (float*)d_out;                        // 4 fp32 scalars
    float* part = (float*)d_ws;                        // 3*NBLK floats

    yolo_main<<<dim3(CHUNKS, BS), 256, 0, stream>>>(inp, tb, tc, part);
    yolo_fin<<<1, 256, 0, stream>>>(part, out);
}